// Round 10
// baseline (15339.398 us; speedup 1.0000x reference)
//
#include <hip/hip_runtime.h>

// ---------------------------------------------------------------------------
// 2-layer LSTM (H=51) + Linear(51,1), B=1024, T=1024, fp32.
// R23 = two-block layer pipeline: L1-blocks and L2-blocks on SEPARATE CUs.
//   Post-mortem R22: burst-shrink confirmed (conflicts 1.76e7->1.47e7, ratio
//   matches read-count model) but only -6%: one shared barrier serializes
//   both wave-groups through one CU's DS+VALU pipes; 64 CUs = 25% of chip.
//   In-block levers exhausted (R17-R22). The layer split is the only
//   decomposition that halves per-CU work.
//   - 128 blocks x 13 waves (832 thr): blocks 0..63 = L1 for group g,
//     blocks 64..127 = L2 for group g. Each block: own recurrence in own
//     LDS, own 13-wave barrier, HALF the per-step instructions.
//   - h1 handoff: __device__ ring g_h1ring[g][4][16][64] (zero-init; lands
//     in the shared XCD L2 - blocks g and g+64 are both XCD g%8 under
//     round-robin). Flags prog1/prog2 in d_ws, zeroed by hipMemsetAsync
//     each launch (graph-capturable).
//   - Protocol (deadlock-free: mutual block needs k>j+7 AND k<j+2):
//     L1 step k: publish prog1=k at top (after prior barrier+vmcnt drain);
//       early-load prog2; compute; spin prog2>=k-3 before ring overwrite;
//       write LDS + ring; s_waitcnt vmcnt(0) lgkmcnt(0); s_barrier.
//     L2 step j: publish prog2=j; vmcnt-pin-wait prefetched B1=h1(j);
//       early-load prog1; compute L2(j) (+y(j-1) on wave 0 from B2 regs);
//       spin prog1>=j+2; prefetch h1(j+1) via sc0 loads (bypass stale L1$,
//       latency hidden under next step); lgkm-only barrier.
//   - Math bit-identical to R22: fp16 single-term MFMA, fused-rcp cells,
//     exp2-domain gates, posu/ipos layout, KPAD=88 LDS (conflict-free b128).
// ---------------------------------------------------------------------------

#define H     51
#define NROW  204      // 4*H
#define TLEN  1024
#define BPB   16       // batches per block (= mfma N)
#define NTHR  832      // 13 waves
#define NG    64       // batch groups
#define NBLK  (2*NG)   // 64 L1-blocks + 64 L2-blocks
#define KPAD  88       // LDS row stride (176B) -> conflict-free b128 reads
#define GW    64       // global ring row width (positions 0..63)
#define RING  4

#define LOG2E  1.442695041f
#define LOG2E2 2.885390082f

typedef __attribute__((ext_vector_type(8))) _Float16 half8;  // 8 f16 = 4 VGPRs
typedef __attribute__((ext_vector_type(4))) float f4;

// h1 ring: zero-initialized at module load; pad positions never written.
__device__ __align__(16) _Float16 g_h1ring[NG][RING][BPB][GW];

__device__ __forceinline__ float frcp(float x) { return __builtin_amdgcn_rcpf(x); }
#if __has_builtin(__builtin_amdgcn_exp2f)
__device__ __forceinline__ float ex2(float x) { return __builtin_amdgcn_exp2f(x); }
#else
__device__ __forceinline__ float ex2(float x) { return __expf(x * 0.6931471806f); }
#endif

// k-layout permutation within each 8-group (R20-proven exact relabeling).
__device__ __forceinline__ int posu(int u) {
    return (u & ~7) | ((u & 3) << 1) | ((u >> 2) & 1);
}
__device__ __forceinline__ int ipos(int p) {
    return (p & ~7) | ((p & 1) << 2) | ((p >> 1) & 3);
}

__device__ __forceinline__ half8 lds8h(const _Float16* p) {  // ds_read_b128
    return *(const half8*)__builtin_assume_aligned(p, 16);
}

// Device-scope flag ops (cross-block, XCD-L2 coherent).
__device__ __forceinline__ int aload(int* p) {
    return __hip_atomic_load(p, __ATOMIC_ACQUIRE, __HIP_MEMORY_SCOPE_AGENT);
}
__device__ __forceinline__ void astore(int* p, int v) {
    __hip_atomic_store(p, v, __ATOMIC_RELEASE, __HIP_MEMORY_SCOPE_AGENT);
}

// sc0 (L1-bypassing, L2-coherent) 16B load; pin-wait before use rewires the
// dest so the compiler cannot hoist consumers above the waitcnt (rule #18).
__device__ __forceinline__ void gload16_sc0(const _Float16* p, half8* d) {
    asm volatile("global_load_dwordx4 %0, %1, off sc0"
                 : "=v"(*d) : "v"(p) : "memory");
}
__device__ __forceinline__ void wait_vm0_pin(half8* a, half8* b) {
    asm volatile("s_waitcnt vmcnt(0)" : "+v"(*a), "+v"(*b));
}

#define MFMA(ACC, A, B) \
    ACC = __builtin_amdgcn_mfma_f32_16x16x32_f16((A), (B), (ACC), 0, 0, 0)

// A-frag loader (R20-proven): prow=4u+g row permutation, ipos'd k columns,
// zero-pad prow>=204 / unit>=51, log2e / 2log2e pre-scaling.
__device__ __forceinline__ half8 load_wfrag(const float* __restrict__ W,
                                            int tile, int kt, int q, int mcol)
{
    half8 hf;
    const int prow = tile * 16 + mcol;
    const float sc = ((prow & 3) == 2) ? LOG2E2 : LOG2E;
#pragma unroll
    for (int j = 0; j < 8; ++j) {
        const int kk = ipos(kt * 32 + q * 8 + j);
        float v = 0.0f;
        if (prow < NROW && kk < H) {
            const int srow = (prow & 3) * H + (prow >> 2);
            v = W[srow * H + kk];
        }
        hf[j] = (_Float16)(v * sc);
    }
    return hf;
}

// Fused LSTM cell (exp2-domain), 5 ex2 + 3 rcp. All-zero gates -> h = 0.
__device__ __forceinline__ float cell(float a_i, float a_f, float b_g,
                                      float d_o, float* c)
{
    const float e_i = ex2(-a_i);
    const float e_f = ex2(-a_f);
    const float Eg  = ex2(b_g);
    const float f   = frcp(1.0f + e_f);
    const float ig  = (Eg - 1.0f) * frcp((1.0f + e_i) * (Eg + 1.0f));
    const float cn  = fmaf(f, *c, ig);
    *c = cn;
    const float Ec  = ex2(cn * LOG2E2);
    const float e_o = ex2(-d_o);
    return (Ec - 1.0f) * frcp((Ec + 1.0f) * (1.0f + e_o));
}

__global__
__attribute__((amdgpu_flat_work_group_size(NTHR, NTHR), amdgpu_waves_per_eu(4, 4)))
void lstm2_kernel(const float* __restrict__ input,
                  const float* __restrict__ W_ih1, const float* __restrict__ W_hh1,
                  const float* __restrict__ b_ih1, const float* __restrict__ b_hh1,
                  const float* __restrict__ W_ih2, const float* __restrict__ W_hh2,
                  const float* __restrict__ b_ih2, const float* __restrict__ b_hh2,
                  const float* __restrict__ W_lin, const float* __restrict__ b_lin,
                  float* __restrict__ out, int* __restrict__ flags)
{
    const int tid  = threadIdx.x;
    const int w    = tid >> 6;        // wave 0..12
    const int lane = tid & 63;
    const int q    = lane >> 4;
    const int mcol = lane & 15;
    const int role = (int)blockIdx.x >> 6;     // 0 = L1, 1 = L2
    const int g    = (int)blockIdx.x & (NG - 1);
    const int b0   = g * BPB;

    int* prog1 = flags + g;           // steps L1 has published
    int* prog2 = flags + NG + g;      // steps L2 has completed

    // Own-layer h, ping-pong, posu layout. Pad positions stay zero.
    __shared__ __align__(16) _Float16 hloc[2][BPB][KPAD];
    {
        _Float16* hz = &hloc[0][0][0];
        for (int i = tid; i < 2 * BPB * KPAD; i += NTHR) hz[i] = (_Float16)0.0f;
    }

    const int t    = w;               // tile 0..12
    const int u    = 4 * t + q;       // unit (u=51 when t=12,q=3 -> dummy)
    const int wpos = posu(u);

    if (role == 0) {
        // ================= L1 block =================
        half8 A[2];
        f4 bb, wx;
#pragma unroll
        for (int kt = 0; kt < 2; ++kt) A[kt] = load_wfrag(W_hh1, t, kt, q, mcol);
#pragma unroll
        for (int j = 0; j < 4; ++j) {
            const bool v = (u < H);
            const float sc = (j == 2) ? LOG2E2 : LOG2E;
            bb[j] = v ? sc * (b_ih1[j * H + u] + b_hh1[j * H + u]) : 0.0f;
            wx[j] = v ? sc * W_ih1[j * H + u] : 0.0f;
        }
        float c = 0.0f;
        float xcur = input[(size_t)(b0 + mcol) * TLEN + 0];
        __syncthreads();

        for (int k = 0; k < TLEN; ++k) {
            if (tid == 0 && k) astore(prog1, k);      // steps < k published
            int p2v = 0x7fffffff;
            if (k >= RING) p2v = aload(prog2);        // early, hidden latency
            const int kn = (k + 1 < TLEN) ? (k + 1) : (TLEN - 1);
            const float xn = input[(size_t)(b0 + mcol) * TLEN + kn];

            const _Float16* rb = &hloc[(k + 1) & 1][mcol][0];   // h1(k-1)
            half8 B1a = lds8h(rb + q * 8);
            half8 B1b = lds8h(rb + 32 + q * 8);
            f4 g1;
            g1[0] = fmaf(wx[0], xcur, bb[0]);
            g1[1] = fmaf(wx[1], xcur, bb[1]);
            g1[2] = fmaf(wx[2], xcur, bb[2]);
            g1[3] = fmaf(wx[3], xcur, bb[3]);
            MFMA(g1, A[0], B1a);  MFMA(g1, A[1], B1b);
            const float h = cell(g1[0], g1[1], g1[2], g1[3], &c);

            if (k >= RING) {                          // ring-overwrite guard
                while (p2v < k - (RING - 1)) p2v = aload(prog2);
            }
            hloc[k & 1][mcol][wpos] = (_Float16)h;
            g_h1ring[g][k & (RING - 1)][mcol][wpos] = (_Float16)h;
            // drain LDS + ring stores, then barrier; publish happens next step
            asm volatile("s_waitcnt vmcnt(0) lgkmcnt(0)\n\ts_barrier" ::: "memory");
            xcur = xn;
        }
        if (tid == 0) astore(prog1, TLEN);
    } else {
        // ================= L2 block =================
        half8 Wi[2], Wh[2];
        f4 bb;
#pragma unroll
        for (int kt = 0; kt < 2; ++kt) {
            Wi[kt] = load_wfrag(W_ih2, t, kt, q, mcol);
            Wh[kt] = load_wfrag(W_hh2, t, kt, q, mcol);
        }
#pragma unroll
        for (int j = 0; j < 4; ++j) {
            const bool v = (u < H);
            const float sc = (j == 2) ? LOG2E2 : LOG2E;
            bb[j] = v ? sc * (b_ih2[j * H + u] + b_hh2[j * H + u]) : 0.0f;
        }
        float wl_a[8], wl_b[8];                       // wave 0: y weights
        if (w == 0) {
#pragma unroll
            for (int i = 0; i < 8; ++i) {
                const int ra = ipos(q * 8 + i);
                const int rb_ = ipos(32 + q * 8 + i);
                wl_a[i] = (ra < H) ? W_lin[ra] : 0.0f;
                wl_b[i] = (rb_ < H) ? W_lin[rb_] : 0.0f;
            }
        }
        const float blin = b_lin[0];
        float c = 0.0f;
        __syncthreads();

        // prologue: wait for h1(0), prefetch it
        {
            int p1v = aload(prog1);
            while (p1v < 1) { __builtin_amdgcn_s_sleep(2); p1v = aload(prog1); }
        }
        half8 B1a, B1b;
        gload16_sc0(&g_h1ring[g][0][mcol][q * 8], &B1a);
        gload16_sc0(&g_h1ring[g][0][mcol][32 + q * 8], &B1b);

        for (int j = 0; j < TLEN; ++j) {
            if (tid == 0) astore(prog2, j);           // steps < j completed
            wait_vm0_pin(&B1a, &B1b);                 // B1 = h1(j) ready
            int p1v = aload(prog1);                   // early, hidden latency

            const _Float16* rb = &hloc[(j + 1) & 1][mcol][0];   // h2(j-1)
            half8 B2a = lds8h(rb + q * 8);
            half8 B2b = lds8h(rb + 32 + q * 8);
            f4 g2 = bb;
            MFMA(g2, Wi[0], B1a);  MFMA(g2, Wi[1], B1b);
            MFMA(g2, Wh[0], B2a);  MFMA(g2, Wh[1], B2b);

            // y(j-1) on wave 0 from B2 = h2(j-1) (free reads)
            if (w == 0 && j > 0) {
                float yp = 0.0f;
#pragma unroll
                for (int i = 0; i < 8; ++i) {
                    yp += wl_a[i] * (float)B2a[i];
                    yp += wl_b[i] * (float)B2b[i];
                }
                yp += __shfl_xor(yp, 16);
                yp += __shfl_xor(yp, 32);
                if (q == 0) out[(size_t)(b0 + mcol) * TLEN + (j - 1)] = yp + blin;
            }

            const float h = cell(g2[0], g2[1], g2[2], g2[3], &c);
            hloc[j & 1][mcol][wpos] = (_Float16)h;

            if (j + 1 < TLEN) {                       // prefetch h1(j+1)
                while (p1v < j + 2) p1v = aload(prog1);
                gload16_sc0(&g_h1ring[g][(j + 1) & (RING - 1)][mcol][q * 8], &B1a);
                gload16_sc0(&g_h1ring[g][(j + 1) & (RING - 1)][mcol][32 + q * 8], &B1b);
            }
            // lgkm-only: keep prefetch in flight across the barrier
            asm volatile("s_waitcnt lgkmcnt(0)\n\ts_barrier" ::: "memory");
        }

        // epilogue: y(1023) from h2(1023) = hloc slot (TLEN-1)&1 = 1
        if (w == 0) {
            const _Float16* rb = &hloc[1][mcol][0];
            half8 ya = lds8h(rb + q * 8);
            half8 yb = lds8h(rb + 32 + q * 8);
            float yp = 0.0f;
#pragma unroll
            for (int i = 0; i < 8; ++i) {
                yp += wl_a[i] * (float)ya[i];
                yp += wl_b[i] * (float)yb[i];
            }
            yp += __shfl_xor(yp, 16);
            yp += __shfl_xor(yp, 32);
            if (q == 0) out[(size_t)(b0 + mcol) * TLEN + (TLEN - 1)] = yp + blin;
        }
    }
}

extern "C" void kernel_launch(void* const* d_in, const int* in_sizes, int n_in,
                              void* d_out, int out_size, void* d_ws, size_t ws_size,
                              hipStream_t stream)
{
    const float* input = (const float*)d_in[0];
    const float* W_ih1 = (const float*)d_in[1];
    const float* W_hh1 = (const float*)d_in[2];
    const float* b_ih1 = (const float*)d_in[3];
    const float* b_hh1 = (const float*)d_in[4];
    const float* W_ih2 = (const float*)d_in[5];
    const float* W_hh2 = (const float*)d_in[6];
    const float* b_ih2 = (const float*)d_in[7];
    const float* b_hh2 = (const float*)d_in[8];
    const float* W_lin = (const float*)d_in[9];
    const float* b_lin = (const float*)d_in[10];

    float* out  = (float*)d_out;
    int* flags  = (int*)d_ws;

    // Reset progress flags every launch (stream-ordered, graph-capturable).
    hipMemsetAsync(d_ws, 0, 2 * NG * sizeof(int), stream);

    hipLaunchKernelGGL(lstm2_kernel, dim3(NBLK), dim3(NTHR), 0, stream,
                       input, W_ih1, W_hh1, b_ih1, b_hh1,
                       W_ih2, W_hh2, b_ih2, b_hh2, W_lin, b_lin,
                       out, flags);
}

// Round 11
// 803.675 us; speedup vs baseline: 19.0866x; 19.0866x over previous
//
#include <hip/hip_runtime.h>

// ---------------------------------------------------------------------------
// 2-layer LSTM (H=51) + Linear(51,1), B=1024, T=1024, fp32.
// R24 = R22 with the 14-wave s_barrier replaced by TWO 7-wave LDS
//       sum-counter barriers (L1-group, L2-group) -> groups decouple.
//   Post-mortem R23: cross-CU per-step sync = death (15us/step, 219MB
//   writeback). Sync must stay in-CU. R17-R22 accounting: all pipes ~55%,
//   residual ~600cy/step = lockstep skew of ONE 14-wave barrier.
//   - done1/done2 in LDS; each wave atomicAdd(+1) per completed step AFTER
//     lgkmcnt(0) drain (increment visible => h-writes visible).
//   - Waits: L1@k: done1>=7k (h1(k-1)), done2>=7(k-3) (h1-ring WAR).
//            L2@j: done1>=7(j+1) (h1(j)),  done2>=7j (h2(j-1)).
//     Sum-threshold + exactly-1-increment/step == intra-group barrier
//     (spread 0); cross-group window k-3<=j<=k-1; rings 4-deep => race-free;
//     deadlock needs j<=k-4 AND k<=j: impossible.
//   - Spin: volatile LDS read + s_sleep(1) backoff; sched_barrier(0) after
//     each wait (stop hoisting of ds_reads above the gate, rule #18).
//   - Kept from R22 (all proven): 7 fat L1 waves {w,7+w} + 7 fat L2 waves,
//     L2 reads h1(j) direct from 4-deep ring, y folded into wave 7 (free B2
//     regs), fp16 single-term MFMA, fused-rcp cells, exp2-domain gates,
//     posu/ipos layout, KPAD=88 conflict-free b128, waves_per_eu(4,4).
//   Arithmetic bit-identical to R22 -> absmax must stay 4.8828e-4.
// ---------------------------------------------------------------------------

#define H     51
#define NROW  204      // 4*H
#define TLEN  1024
#define BPB   16       // batches per block (= mfma N)
#define NTHR  896      // 14 waves
#define NBLK  64
#define KPAD  88       // fp16 row stride (176B)
#define RING  4

#define LOG2E  1.442695041f
#define LOG2E2 2.885390082f

typedef __attribute__((ext_vector_type(8))) _Float16 half8;  // 8 f16 = 4 VGPRs
typedef __attribute__((ext_vector_type(4))) float f4;

__device__ __forceinline__ float frcp(float x) { return __builtin_amdgcn_rcpf(x); }
#if __has_builtin(__builtin_amdgcn_exp2f)
__device__ __forceinline__ float ex2(float x) { return __builtin_amdgcn_exp2f(x); }
#else
__device__ __forceinline__ float ex2(float x) { return __expf(x * 0.6931471806f); }
#endif

// k-layout permutation within each 8-group (R20-proven exact relabeling).
__device__ __forceinline__ int posu(int u) {
    return (u & ~7) | ((u & 3) << 1) | ((u >> 2) & 1);
}
__device__ __forceinline__ int ipos(int p) {
    return (p & ~7) | ((p & 1) << 2) | ((p >> 1) & 3);
}

__device__ __forceinline__ half8 lds8h(const _Float16* p) {  // ds_read_b128
    return *(const half8*)__builtin_assume_aligned(p, 16);
}

#define MFMA(ACC, A, B) \
    ACC = __builtin_amdgcn_mfma_f32_16x16x32_f16((A), (B), (ACC), 0, 0, 0)

// A-frag loader (R20-proven): prow=4u+g row permutation, ipos'd k columns,
// zero-pad prow>=204 / unit>=51, log2e / 2log2e pre-scaling.
__device__ __forceinline__ half8 load_wfrag(const float* __restrict__ W,
                                            int tile, int kt, int q, int mcol)
{
    half8 hf;
    const int prow = tile * 16 + mcol;
    const float sc = ((prow & 3) == 2) ? LOG2E2 : LOG2E;
#pragma unroll
    for (int j = 0; j < 8; ++j) {
        const int kk = ipos(kt * 32 + q * 8 + j);
        float v = 0.0f;
        if (prow < NROW && kk < H) {
            const int srow = (prow & 3) * H + (prow >> 2);
            v = W[srow * H + kk];
        }
        hf[j] = (_Float16)(v * sc);
    }
    return hf;
}

// Fused LSTM cell (exp2-domain), 5 ex2 + 3 rcp. All-zero gates -> h = 0.
__device__ __forceinline__ float cell(float a_i, float a_f, float b_g,
                                      float d_o, float* c)
{
    const float e_i = ex2(-a_i);
    const float e_f = ex2(-a_f);
    const float Eg  = ex2(b_g);
    const float f   = frcp(1.0f + e_f);
    const float ig  = (Eg - 1.0f) * frcp((1.0f + e_i) * (Eg + 1.0f));
    const float cn  = fmaf(f, *c, ig);
    *c = cn;
    const float Ec  = ex2(cn * LOG2E2);
    const float e_o = ex2(-d_o);
    return (Ec - 1.0f) * frcp((Ec + 1.0f) * (1.0f + e_o));
}

// Spin until *P >= T (volatile LDS read; s_sleep backoff; fence hoisting).
#define WAITGE(P, T)                                                           \
do {                                                                           \
    if (*(P) < (T)) {                                                          \
        do { __builtin_amdgcn_s_sleep(1); } while (*(P) < (T));                \
    }                                                                          \
    __builtin_amdgcn_sched_barrier(0);                                         \
} while (0)

__global__
__attribute__((amdgpu_flat_work_group_size(NTHR, NTHR), amdgpu_waves_per_eu(4, 4)))
void lstm2_kernel(const float* __restrict__ input,
                  const float* __restrict__ W_ih1, const float* __restrict__ W_hh1,
                  const float* __restrict__ b_ih1, const float* __restrict__ b_hh1,
                  const float* __restrict__ W_ih2, const float* __restrict__ W_hh2,
                  const float* __restrict__ b_ih2, const float* __restrict__ b_hh2,
                  const float* __restrict__ W_lin, const float* __restrict__ b_lin,
                  float* __restrict__ out)
{
    const int tid  = threadIdx.x;
    const int w    = tid >> 6;        // wave 0..13
    const int lane = tid & 63;
    const int q    = lane >> 4;
    const int mcol = lane & 15;
    const int b0   = blockIdx.x * BPB;

    const bool isL1 = (w < 7);
    const int  tw   = isL1 ? w : (w - 7);

    // 4-deep rings (slot = step mod 4), posu k-layout. Pad stays zero.
    __shared__ __align__(16) _Float16 h1r[RING][BPB][KPAD];
    __shared__ __align__(16) _Float16 h2r[RING][BPB][KPAD];
    __shared__ int dflag[16];         // [0]=done1, [8]=done2 (padded apart)

    {
        _Float16* p1 = &h1r[0][0][0];
        for (int i = tid; i < RING * BPB * KPAD; i += NTHR) p1[i] = (_Float16)0.0f;
        _Float16* p2 = &h2r[0][0][0];
        for (int i = tid; i < RING * BPB * KPAD; i += NTHR) p2[i] = (_Float16)0.0f;
        if (tid < 16) dflag[tid] = 0;
    }
    volatile int* d1 = &dflag[0];
    volatile int* d2 = &dflag[8];

    // ---- persistent per-wave state (R22 roles) -----------------------------
    half8 Wa[2][2], Wb[2][2];
    f4 bbv[2], wxv[2];
    float cc[2] = {0.0f, 0.0f};
    int wp[2];
    const int tt[2] = {tw, 7 + tw};       // slot1 t=13 (waves 6/13) = dummy
#pragma unroll
    for (int s = 0; s < 2; ++s) {
        const int t = tt[s];
        const int u = 4 * t + q;
        wp[s] = posu(u);
#pragma unroll
        for (int kt = 0; kt < 2; ++kt) {
            if (isL1) {
                Wa[s][kt] = load_wfrag(W_hh1, t, kt, q, mcol);
            } else {
                Wa[s][kt] = load_wfrag(W_ih2, t, kt, q, mcol);
                Wb[s][kt] = load_wfrag(W_hh2, t, kt, q, mcol);
            }
        }
#pragma unroll
        for (int j = 0; j < 4; ++j) {
            const bool v = (t < 13) && (u < H);
            const float sc = (j == 2) ? LOG2E2 : LOG2E;
            if (isL1) {
                bbv[s][j] = v ? sc * (b_ih1[j * H + u] + b_hh1[j * H + u]) : 0.0f;
                wxv[s][j] = v ? sc * W_ih1[j * H + u] : 0.0f;
            } else {
                bbv[s][j] = v ? sc * (b_ih2[j * H + u] + b_hh2[j * H + u]) : 0.0f;
                wxv[s][j] = 0.0f;
            }
        }
    }

    float wl_a[8], wl_b[8];               // wave 7: y weights per k-position
    if (w == 7) {
#pragma unroll
        for (int j = 0; j < 8; ++j) {
            const int ra = ipos(q * 8 + j);
            const int rb = ipos(32 + q * 8 + j);
            wl_a[j] = (ra < H) ? W_lin[ra] : 0.0f;
            wl_b[j] = (rb < H) ? W_lin[rb] : 0.0f;
        }
    }
    const float blin = b_lin[0];

    float xcur = isL1 ? input[(size_t)(b0 + mcol) * TLEN + 0] : 0.0f;

    __syncthreads();                      // zeros + flags visible (only barrier)

// ---- L1 step k: read h1(k-1) slot SR, write h1(k) slot SW ----------------
#define L1STEP(KK, SW, SR, W1, W2)                                             \
do {                                                                           \
    const int k_  = (KK);                                                      \
    const int kn_ = (k_ + 1 < TLEN) ? (k_ + 1) : (TLEN - 1);                   \
    const float xn_ = input[(size_t)(b0 + mcol) * TLEN + kn_];                 \
    if (W1) WAITGE(d1, 7 * k_);                                                \
    if (W2) WAITGE(d2, 7 * (k_ - 3));                                          \
    half8 B1a = lds8h(&h1r[SR][mcol][q * 8]);                                  \
    half8 B1b = lds8h(&h1r[SR][mcol][32 + q * 8]);                             \
    f4 g0, g1;                                                                 \
    g0[0] = fmaf(wxv[0][0], xcur, bbv[0][0]);                                  \
    g0[1] = fmaf(wxv[0][1], xcur, bbv[0][1]);                                  \
    g0[2] = fmaf(wxv[0][2], xcur, bbv[0][2]);                                  \
    g0[3] = fmaf(wxv[0][3], xcur, bbv[0][3]);                                  \
    g1[0] = fmaf(wxv[1][0], xcur, bbv[1][0]);                                  \
    g1[1] = fmaf(wxv[1][1], xcur, bbv[1][1]);                                  \
    g1[2] = fmaf(wxv[1][2], xcur, bbv[1][2]);                                  \
    g1[3] = fmaf(wxv[1][3], xcur, bbv[1][3]);                                  \
    MFMA(g0, Wa[0][0], B1a);  MFMA(g0, Wa[0][1], B1b);                         \
    MFMA(g1, Wa[1][0], B1a);  MFMA(g1, Wa[1][1], B1b);                         \
    const float h0  = cell(g0[0], g0[1], g0[2], g0[3], &cc[0]);                \
    const float h1v = cell(g1[0], g1[1], g1[2], g1[3], &cc[1]);                \
    h1r[SW][mcol][wp[0]] = (_Float16)h0;                                       \
    h1r[SW][mcol][wp[1]] = (_Float16)h1v;                                      \
    asm volatile("s_waitcnt lgkmcnt(0)" ::: "memory");                         \
    if (lane == 0) atomicAdd(&dflag[0], 1);                                    \
    xcur = xn_;                                                                \
} while (0)

// ---- L2 step j: read h1(j) slot SW, h2(j-1) slot SR2; write h2(j) SW -----
#define L2STEP(JJ, SW, SR2, W2, YE)                                            \
do {                                                                           \
    const int j_ = (JJ);                                                       \
    WAITGE(d1, 7 * (j_ + 1));                                                  \
    if (W2) WAITGE(d2, 7 * j_);                                                \
    half8 B1a = lds8h(&h1r[SW][mcol][q * 8]);                                  \
    half8 B1b = lds8h(&h1r[SW][mcol][32 + q * 8]);                             \
    half8 B2a = lds8h(&h2r[SR2][mcol][q * 8]);                                 \
    half8 B2b = lds8h(&h2r[SR2][mcol][32 + q * 8]);                            \
    f4 g0 = bbv[0], g1 = bbv[1];                                               \
    MFMA(g0, Wa[0][0], B1a);  MFMA(g0, Wa[0][1], B1b);                         \
    MFMA(g1, Wa[1][0], B1a);  MFMA(g1, Wa[1][1], B1b);                         \
    MFMA(g0, Wb[0][0], B2a);  MFMA(g0, Wb[0][1], B2b);                         \
    MFMA(g1, Wb[1][0], B2a);  MFMA(g1, Wb[1][1], B2b);                         \
    if ((YE) && w == 7) {             /* y(j-1) from B2 = h2(j-1), free */     \
        float yp = 0.0f;                                                       \
        _Pragma("unroll")                                                      \
        for (int i = 0; i < 8; ++i) {                                          \
            yp += wl_a[i] * (float)B2a[i];                                     \
            yp += wl_b[i] * (float)B2b[i];                                     \
        }                                                                      \
        yp += __shfl_xor(yp, 16);                                              \
        yp += __shfl_xor(yp, 32);                                              \
        if (q == 0) out[(size_t)(b0 + mcol) * TLEN + (j_ - 1)] = yp + blin;    \
    }                                                                          \
    const float h0  = cell(g0[0], g0[1], g0[2], g0[3], &cc[0]);                \
    const float h1v = cell(g1[0], g1[1], g1[2], g1[3], &cc[1]);                \
    h2r[SW][mcol][wp[0]] = (_Float16)h0;                                       \
    h2r[SW][mcol][wp[1]] = (_Float16)h1v;                                      \
    asm volatile("s_waitcnt lgkmcnt(0)" ::: "memory");                         \
    if (lane == 0) atomicAdd(&dflag[8], 1);                                    \
} while (0)

    if (isL1) {
        L1STEP(0, 0, 3, 0, 0);            // h1(-1) = slot 3 zeros
        L1STEP(1, 1, 0, 1, 0);
        L1STEP(2, 2, 1, 1, 0);
        L1STEP(3, 3, 2, 1, 0);
        for (int k = 4; k < TLEN; k += 4) {
            L1STEP(k + 0, 0, 3, 1, 1);
            L1STEP(k + 1, 1, 0, 1, 1);
            L1STEP(k + 2, 2, 1, 1, 1);
            L1STEP(k + 3, 3, 2, 1, 1);
        }
    } else {
        L2STEP(0, 0, 3, 0, 0);            // h2(-1) = slot 3 zeros
        L2STEP(1, 1, 0, 1, 1);
        L2STEP(2, 2, 1, 1, 1);
        L2STEP(3, 3, 2, 1, 1);
        for (int j = 4; j < TLEN; j += 4) {
            L2STEP(j + 0, 0, 3, 1, 1);
            L2STEP(j + 1, 1, 0, 1, 1);
            L2STEP(j + 2, 2, 1, 1, 1);
            L2STEP(j + 3, 3, 2, 1, 1);
        }
        // epilogue: y(1023) from h2(1023) = slot 1023%4 = 3 (all L2 done)
        if (w == 7) {
            WAITGE(d2, 7 * TLEN);
            half8 ya = lds8h(&h2r[3][mcol][q * 8]);
            half8 yb = lds8h(&h2r[3][mcol][32 + q * 8]);
            float yp = 0.0f;
#pragma unroll
            for (int i = 0; i < 8; ++i) {
                yp += wl_a[i] * (float)ya[i];
                yp += wl_b[i] * (float)yb[i];
            }
            yp += __shfl_xor(yp, 16);
            yp += __shfl_xor(yp, 32);
            if (q == 0) out[(size_t)(b0 + mcol) * TLEN + (TLEN - 1)] = yp + blin;
        }
    }
#undef L1STEP
#undef L2STEP
}

extern "C" void kernel_launch(void* const* d_in, const int* in_sizes, int n_in,
                              void* d_out, int out_size, void* d_ws, size_t ws_size,
                              hipStream_t stream)
{
    const float* input = (const float*)d_in[0];
    const float* W_ih1 = (const float*)d_in[1];
    const float* W_hh1 = (const float*)d_in[2];
    const float* b_ih1 = (const float*)d_in[3];
    const float* b_hh1 = (const float*)d_in[4];
    const float* W_ih2 = (const float*)d_in[5];
    const float* W_hh2 = (const float*)d_in[6];
    const float* b_ih2 = (const float*)d_in[7];
    const float* b_hh2 = (const float*)d_in[8];
    const float* W_lin = (const float*)d_in[9];
    const float* b_lin = (const float*)d_in[10];

    float* out = (float*)d_out;

    hipLaunchKernelGGL(lstm2_kernel, dim3(NBLK), dim3(NTHR), 0, stream,
                       input, W_ih1, W_hh1, b_ih1, b_hh1,
                       W_ih2, W_hh2, b_ih2, b_hh2, W_lin, b_lin,
                       out);
}